// Round 9
// baseline (159.753 us; speedup 1.0000x reference)
//
#include <hip/hip_runtime.h>
#include <hip/hip_fp16.h>

#define Q_TOT 1024
#define T_TOT 256
#define NPTS  100
#define KD    300
#define EPSV  1e-6f

#define KSTEPS 10            // 10 * 32 = 320 >= 300 (zero-padded K)
#define EXTOFF 40            // front zero-pad for padded rows
#define EXTLEN 672           // f16 units per rotated copy

// Copy placement (R20).  Copy c at f16 base CB[c] inside each SEL region.
#define SSTR 5696            // f16 per SEL region (11392 B, mult of 128)
#define CB_0 4280
#define CB_1 4984
#define CB_2 720
#define CB_3 1424
#define CB_4 2128
#define CB_5 2856
#define CB_6 3560
#define CB_7 0

typedef _Float16 f16;
typedef _Float16 f16x8 __attribute__((ext_vector_type(8)));
typedef float    f32x4 __attribute__((ext_vector_type(4)));
#define MFMA16 __builtin_amdgcn_mfma_f32_16x16x32_f16

// ws layout (floats): [0,1024) p2[q]; [1024,1280) v2[t]; [1280,+327680) pfrag
#define WS_PF 1280

// ---------------------------------------------------------------------------
// Prep: 64 blocks x 256; block b owns N-tile b.  (R18-verified numerics;
// unchanged.)
// ---------------------------------------------------------------------------
__global__ __launch_bounds__(256) void prep_all(const float* __restrict__ preds,
                                                const float* __restrict__ tgt,
                                                float* __restrict__ ws)
{
    __shared__ __align__(16) float ext[16][308];
    const int b   = blockIdx.x;          // = nt
    const int tid = threadIdx.x;

    {
        const float4* src = (const float4*)(preds + b*16*KD);
        for (int i = tid; i < 1200; i += 256) {
            int row = i / 75;
            int c   = i - row*75;
            *(float4*)&ext[row][c*4] = src[i];
        }
    }
    __syncthreads();

    f16x8* pf = (f16x8*)(ws + WS_PF) + b*1280;
    for (int j = tid; j < 1280; j += 256) {
        int lane = j & 63;
        int r    = j >> 6;               // = ks*2 + s
        int s    = r & 1;
        int ks   = r >> 1;
        int qr   = lane & 15;
        int kb   = ks*32 + (lane >> 4)*8;
        f16x8 v;
        #pragma unroll
        for (int jj = 0; jj < 8; ++jj) {
            int k = kb + jj;
            float x = (k < KD) ? ext[qr][k] : 0.f;
            f16 h = (f16)x;
            v[jj] = s ? (f16)(x - (float)h) : h;
        }
        pf[j] = v;
    }

    const int wv   = tid >> 6;           // 0..3
    const int lane = tid & 63;
    #pragma unroll
    for (int rr = 0; rr < 4; ++rr) {
        int row = wv*4 + rr;
        float s = 0.f;
        for (int k = lane; k < KD; k += 64) s = fmaf(ext[row][k], ext[row][k], s);
        #pragma unroll
        for (int m = 1; m < 64; m <<= 1) s += __shfl_xor(s, m, 64);
        if (lane == 0) ws[b*16 + row] = s;
    }
    {
        const float* base = tgt + (b*4 + wv)*KD;
        float s = 0.f;
        for (int k = lane; k < KD; k += 64) s = fmaf(base[k], base[k], s);
        #pragma unroll
        for (int m = 1; m < 64; m <<= 1) s += __shfl_xor(s, m, 64);
        if (lane == 0) ws[1024 + b*4 + wv] = s;
    }
}

// ---------------------------------------------------------------------------
// R26 sweep: R22 shape (7 M-tiles x 2 N-tiles, 8 waves) with the K-loop
// VALU stripped.  Evidence: MfmaUtil+VALUBusy ~= 96% in BOTH R22 and R25 ->
// the SIMD issue budget is saturated; per-kstep 64-bit address mads were the
// VALU.  Now: B via 2 pointers bumped +2048B/kstep, loads at imm {1024,2048};
// A via one pointer bumped +64B/kstep, all 14 ds_read_b128 at compile-time
// imm offsets (base biased -288 f16 -> offsets unsigned, max 11968B).  Last
// ks-pair peeled (kills per-iter prefetch clamp).  Addresses bit-identical
// to R22; numerics unchanged.  bh-prefetch + setprio kept.
// ---------------------------------------------------------------------------
template<int SEL, int VOFF>
__device__ __forceinline__ void sweep2(const f16* __restrict__ sflat,
                                       const f16x8* __restrict__ pfrag,
                                       int ntg0, int lane, int col, int rg, int aoff,
                                       float v2t, const float (&p2v)[2],
                                       float (&minD)[2], int (&minI)[2],
                                       float (*sopen)[256], int ntl0)
{
    // A base: lowest address touched this sweep (h=6 bias), so all imm
    // offsets 48*(6-h) [+SSTR for lo] are unsigned.  aoff >= 288 always.
    const f16* ap = sflat + SEL*SSTR + (aoff - 288);
    // B bases: point at bh(ks=0); bl at +64 (1024B), next bh at +128 (2048B).
    const f16x8* p0 = pfrag + (size_t)(ntg0    )*KSTEPS*128 + lane;
    const f16x8* p1 = pfrag + (size_t)(ntg0 + 1)*KSTEPS*128 + lane;

    f32x4 acc[7][2];
    #pragma unroll
    for (int h = 0; h < 7; ++h)
        #pragma unroll
        for (int nt = 0; nt < 2; ++nt) acc[h][nt] = (f32x4){0.f,0.f,0.f,0.f};

    f16x8 bhE[2], bhO[2];
    bhE[0] = p0[0];
    bhE[1] = p1[0];

    // One half-kstep: bl @+1024B, 7 ah @imm, MFMA(bh)+MFMA(bl), 7 alo @imm,
    // prefetch next bh @+2048B, MFMA(alo,bh); then bump pointers one kstep.
    #define HALF(BH, BO)                                                      \
    {                                                                         \
        f16x8 bl[2];                                                          \
        bl[0] = p0[64];                                                       \
        bl[1] = p1[64];                                                       \
        f16x8 ah[7];                                                          \
        _Pragma("unroll")                                                     \
        for (int h = 0; h < 7; ++h)                                           \
            ah[h] = *(const f16x8*)&ap[48*(6-h)];                             \
        __builtin_amdgcn_s_setprio(1);                                        \
        _Pragma("unroll")                                                     \
        for (int nt = 0; nt < 2; ++nt)                                        \
            _Pragma("unroll")                                                 \
            for (int h = 0; h < 7; ++h)                                       \
                acc[h][nt] = MFMA16(ah[h], BH[nt], acc[h][nt], 0,0,0);        \
        _Pragma("unroll")                                                     \
        for (int nt = 0; nt < 2; ++nt)                                        \
            _Pragma("unroll")                                                 \
            for (int h = 0; h < 7; ++h)                                       \
                acc[h][nt] = MFMA16(ah[h], bl[nt], acc[h][nt], 0,0,0);        \
        __builtin_amdgcn_s_setprio(0);                                        \
        f16x8 alo[7];                                                         \
        _Pragma("unroll")                                                     \
        for (int h = 0; h < 7; ++h)                                           \
            alo[h] = *(const f16x8*)&ap[48*(6-h) + SSTR];                     \
        if (BO) { (BO)[0] = p0[128]; (BO)[1] = p1[128]; }                     \
        __builtin_amdgcn_s_setprio(1);                                        \
        _Pragma("unroll")                                                     \
        for (int nt = 0; nt < 2; ++nt)                                        \
            _Pragma("unroll")                                                 \
            for (int h = 0; h < 7; ++h)                                       \
                acc[h][nt] = MFMA16(alo[h], BH[nt], acc[h][nt], 0,0,0);       \
        __builtin_amdgcn_s_setprio(0);                                        \
        ap += 32;  p0 += 128;  p1 += 128;                                     \
    }

    #pragma clang loop unroll(disable)
    for (int it = 0; it < 4; ++it) {      // ks pairs (0,1)..(6,7)
        HALF(bhE, bhO)                    // even kstep, prefetch odd bh
        HALF(bhO, bhE)                    // odd kstep, prefetch next even bh
    }
    HALF(bhE, bhO)                        // ks=8, prefetch ks=9 bh
    HALF(bhO, (f16x8*)nullptr)            // ks=9, no prefetch
    #undef HALF

    #pragma unroll
    for (int h = 0; h < 7; ++h) {
        const int ab = h*16 + rg*4;
        #pragma unroll
        for (int nt = 0; nt < 2; ++nt) {
            const float s2 = v2t + p2v[nt];
            #pragma unroll
            for (int r = 0; r < 4; ++r) {
                const int al = ab + r;
                if (al < 100) {
                    float d2 = fmaxf(fmaf(-2.f, acc[h][nt][r], s2), 0.f) * 0.01f;
                    int vlog = VOFF + al;
                    if (d2 < minD[nt]) { minD[nt] = d2; minI[nt] = vlog; }
                    if (al == 0) sopen[VOFF ? 1 : 0][(ntl0+nt)*16 + col] = d2;
                }
            }
        }
    }
}

// ---------------------------------------------------------------------------
// One block = one target t x 256 queries (blockIdx.y quarters N).  8 waves x
// 2 N-tiles; 2 sweeps (fwd, bwd).  LDS overlay (R23): redD/redI on dead
// sflat; block = 47616 B.
// ---------------------------------------------------------------------------
__global__ __launch_bounds__(512) void matcher_mfma(
    const float* __restrict__ ws,      // p2 / v2 / pfrag
    const float* __restrict__ tgt,     // [256][300]
    const float* __restrict__ plog,    // [1024][2]
    const float* __restrict__ ptyp,    // [1024][4]
    const float* __restrict__ clog,    // [1024][2]
    const int*   __restrict__ labels,  // [256]
    const int*   __restrict__ iscl,    // [256]
    const float* __restrict__ clw,     // [256]
    float* __restrict__ out)           // [2][1024][256] flat fp32
{
    __shared__ __align__(16) f16 sflat[4*SSTR]; // {Fh,Fl,Rh,Rl} x 8 placed copies
    __shared__ float sopen[2][256];
    // Overlay (valid only after the post-sweep barrier):
    float* redD = (float*)sflat;                 // [1024]  (4 KB)
    int*   redI = (int*)sflat + 1024;            // [1024]  (4 KB)

    const int t    = blockIdx.x;
    const int nb   = blockIdx.y;        // 0..3
    const int tid  = threadIdx.x;
    const int lane = tid & 63;
    const int w    = tid >> 6;
    const int col  = lane & 15;
    const int rg   = lane >> 4;
    const int ntl0 = w*2;               // local N-tile base (0..14)
    const int ntg0 = nb*16 + ntl0;      // global N-tile base

    // Stage ext (fwd+rev, hi+lo split, 8 rotated copies).  R23 form.
    const float* tg = tgt + t*KD;
    for (int x = tid; x < EXTLEN; x += 512) {
        int e = x - EXTOFF;
        float vF = 0.f, vR = 0.f;
        if (e >= 0 && e < 600) {
            int m = (e >= 300) ? e - 300 : e;
            vF = tg[m];
            int jj = m / 3, c3 = m - 3*jj;
            vR = tg[(NPTS-1-jj)*3 + c3];
        }
        f16 fh = (f16)vF, fl = (f16)(vF - (float)fh);
        f16 rh = (f16)vR, rl = (f16)(vR - (float)rh);
        constexpr int CB[8] = {CB_0,CB_1,CB_2,CB_3,CB_4,CB_5,CB_6,CB_7};
        #pragma unroll
        for (int c = 0; c < 8; ++c) {
            int y = x - c;
            if (y >= 0) {
                const int o = CB[c] + y;      // CB[c] compile-time (unrolled)
                sflat[0*SSTR + o] = fh; sflat[1*SSTR + o] = fl;
                sflat[2*SSTR + o] = rh; sflat[3*SSTR + o] = rl;
            }
        }
    }

    const float v2t = ws[1024 + t];
    float p2v[2];
    #pragma unroll
    for (int nt = 0; nt < 2; ++nt) p2v[nt] = ws[(ntg0+nt)*16 + col];
    const f16x8* __restrict__ pfrag = (const f16x8*)(ws + WS_PF);

    // Per-lane rotation copy and A-read base offset.
    const int cA = (EXTOFF + 300 - 3*col) & 7;   // lane-fixed
    const int cb = (cA==0) ? CB_0 : (cA==1) ? CB_1 : (cA==2) ? CB_2 :
                   (cA==3) ? CB_3 : (cA==4) ? CB_4 : (cA==5) ? CB_5 :
                   (cA==6) ? CB_6 : CB_7;        // cndmask chain, once
    const int aoff = cb - cA + EXTOFF + 300 - 3*col + 8*rg;   // >= 288 always
    __syncthreads();

    float minD[2]; int minI[2];
    #pragma unroll
    for (int nt = 0; nt < 2; ++nt) { minD[nt] = 3.4028235e38f; minI[nt] = 0; }

    sweep2<0,  0>(sflat, pfrag, ntg0, lane, col, rg, aoff, v2t, p2v, minD, minI, sopen, ntl0);
    sweep2<2,100>(sflat, pfrag, ntg0, lane, col, rg, aoff, v2t, p2v, minD, minI, sopen, ntl0);

    __syncthreads();                    // all waves done READING sflat
    #pragma unroll
    for (int nt = 0; nt < 2; ++nt) {
        redD[(ntl0+nt)*64 + lane] = minD[nt];
        redI[(ntl0+nt)*64 + lane] = minI[nt];
    }
    __syncthreads();

    // Epilogue: threads 0..255, one local query each.
    if (tid < 256) {
        const int lq   = tid;
        const int tile = lq >> 4;
        const int cc   = lq & 15;
        const int base = tile*64 + cc;
        float bd = redD[base]; int bi = redI[base];
        #pragma unroll
        for (int g = 1; g < 4; ++g) {
            float d = redD[base + g*16]; int i = redI[base + g*16];
            if (d < bd || (d == bd && i < bi)) { bd = d; bi = i; }
        }
        const int q = nb*256 + lq;
        int mapped = (bi <= NPTS-1) ? bi : (2*NPTS-1 - bi);
        float od   = fminf(sopen[0][lq], sopen[1][lq]);
        int   isc  = iscl[t];
        float geom = isc ? bd : od;
        int   ido  = isc ? mapped : 0;
        geom *= clw[t];

        float t0 = ptyp[q*4+0], t1 = ptyp[q*4+1];
        float t2 = ptyp[q*4+2], t3 = ptyp[q*4+3];
        float mx = fmaxf(fmaxf(t0,t1), fmaxf(t2,t3));
        float e0 = expf(t0-mx), e1 = expf(t1-mx), e2 = expf(t2-mx), e3 = expf(t3-mx);
        float rs = 1.0f/(e0+e1+e2+e3);
        int lab  = labels[t];
        float el = (lab == 0) ? e0 : (lab == 1) ? e1 : (lab == 2) ? e2 : e3;
        float cost = -logf(el*rs + EPSV);
        float v0 = plog[q*2+0], v1 = plog[q*2+1];
        cost += -logf(1.0f/(1.0f + expf(v1-v0)) + EPSV);
        float c0 = clog[q*2+0], c1 = clog[q*2+1];
        float pc = isc ? (1.0f/(1.0f + expf(c0-c1))) : (1.0f/(1.0f + expf(c1-c0)));
        cost += -logf(pc + EPSV);

        float C = geom + cost;
        out[q*T_TOT + t]               = C;
        out[Q_TOT*T_TOT + q*T_TOT + t] = (float)ido;
    }
}

extern "C" void kernel_launch(void* const* d_in, const int* in_sizes, int n_in,
                              void* d_out, int out_size, void* d_ws, size_t ws_size,
                              hipStream_t stream)
{
    const float* preds  = (const float*)d_in[0];  // pred_curve_points (1,1024,100,3)
    const float* plog   = (const float*)d_in[1];  // pred_curve_logits (1,1024,2)
    const float* ptyp   = (const float*)d_in[2];  // pred_curve_type   (1,1024,4)
    const float* clog   = (const float*)d_in[3];  // closed_curve_logits (1,1024,2)
    const float* tgt    = (const float*)d_in[4];  // tgt_curve_points  (256,100,3)
    const int*   labels = (const int*)d_in[5];    // tgt_labels (256)
    const int*   iscl   = (const int*)d_in[6];    // tgt_is_closed (256)
    const float* clw    = (const float*)d_in[7];  // curve_length_weighting (256)
    float* out = (float*)d_out;
    float* ws  = (float*)d_ws;    // 1280 + 327680 floats = 1.32 MB

    prep_all    <<<dim3(64),       dim3(256), 0, stream>>>(preds, tgt, ws);
    matcher_mfma<<<dim3(T_TOT, 4), dim3(512), 0, stream>>>(
        ws, tgt, plog, ptyp, clog, labels, iscl, clw, out);
}

// Round 10
// 155.234 us; speedup vs baseline: 1.0291x; 1.0291x over previous
//
#include <hip/hip_runtime.h>
#include <hip/hip_fp16.h>

#define Q_TOT 1024
#define T_TOT 256
#define NPTS  100
#define KD    300
#define EPSV  1e-6f

#define KSTEPS 10            // 10 * 32 = 320 >= 300 (zero-padded K)
#define EXTOFF 40            // front zero-pad for padded rows
#define EXTLEN 672           // f16 units per rotated copy

// Bank-deconflicted copy placement (R20).  Copy c at f16 base CB[c] inside
// each SEL region; byte base mod 128 = 16*{7,7,2,2,2,5,5,0} -> every 16-lane
// A-read group tiles the eight 16B bank-slot groups exactly 2x (free 2-way).
#define SSTR 5696            // f16 per SEL region (11392 B, mult of 128)
#define CB_0 4280
#define CB_1 4984
#define CB_2 720
#define CB_3 1424
#define CB_4 2128
#define CB_5 2856
#define CB_6 3560
#define CB_7 0

typedef _Float16 f16;
typedef _Float16 f16x8 __attribute__((ext_vector_type(8)));
typedef float    f32x4 __attribute__((ext_vector_type(4)));
#define MFMA16 __builtin_amdgcn_mfma_f32_16x16x32_f16

// ws layout (floats): [0,1024) p2[q]; [1024,1280) v2[t]; [1280,+327680) pfrag
#define WS_PF 1280

// ---------------------------------------------------------------------------
// Prep: 64 blocks x 256; block b owns N-tile b.  (R18-verified numerics;
// unchanged.)
// ---------------------------------------------------------------------------
__global__ __launch_bounds__(256) void prep_all(const float* __restrict__ preds,
                                                const float* __restrict__ tgt,
                                                float* __restrict__ ws)
{
    __shared__ __align__(16) float ext[16][308];
    const int b   = blockIdx.x;          // = nt
    const int tid = threadIdx.x;

    {
        const float4* src = (const float4*)(preds + b*16*KD);
        for (int i = tid; i < 1200; i += 256) {
            int row = i / 75;
            int c   = i - row*75;
            *(float4*)&ext[row][c*4] = src[i];
        }
    }
    __syncthreads();

    f16x8* pf = (f16x8*)(ws + WS_PF) + b*1280;
    for (int j = tid; j < 1280; j += 256) {
        int lane = j & 63;
        int r    = j >> 6;               // = ks*2 + s
        int s    = r & 1;
        int ks   = r >> 1;
        int qr   = lane & 15;
        int kb   = ks*32 + (lane >> 4)*8;
        f16x8 v;
        #pragma unroll
        for (int jj = 0; jj < 8; ++jj) {
            int k = kb + jj;
            float x = (k < KD) ? ext[qr][k] : 0.f;
            f16 h = (f16)x;
            v[jj] = s ? (f16)(x - (float)h) : h;
        }
        pf[j] = v;
    }

    const int wv   = tid >> 6;           // 0..3
    const int lane = tid & 63;
    #pragma unroll
    for (int rr = 0; rr < 4; ++rr) {
        int row = wv*4 + rr;
        float s = 0.f;
        for (int k = lane; k < KD; k += 64) s = fmaf(ext[row][k], ext[row][k], s);
        #pragma unroll
        for (int m = 1; m < 64; m <<= 1) s += __shfl_xor(s, m, 64);
        if (lane == 0) ws[b*16 + row] = s;
    }
    {
        const float* base = tgt + (b*4 + wv)*KD;
        float s = 0.f;
        for (int k = lane; k < KD; k += 64) s = fmaf(base[k], base[k], s);
        #pragma unroll
        for (int m = 1; m < 64; m <<= 1) s += __shfl_xor(s, m, 64);
        if (lane == 0) ws[1024 + b*4 + wv] = s;
    }
}

// ---------------------------------------------------------------------------
// R22 sweep body (session best, 86.2-87.0 us matcher): bh-only prefetch,
// loop-local bl/ah/alo, distinct bhE/bhO locals, setprio around MFMA
// clusters.  The next half-step's bh issues during the current half's
// alo-MFMA phase (covered by 14 MFMAs).  Peak live ~124 regs <= 128,
// 4 waves/SIMD.
// ---------------------------------------------------------------------------
template<int SEL, int VOFF>
__device__ __forceinline__ void sweep2(const f16* __restrict__ sflat,
                                       const f16x8* __restrict__ pfrag,
                                       int ntg0, int lane, int col, int rg, int aoff,
                                       float v2t, const float (&p2v)[2],
                                       float (&minD)[2], int (&minI)[2],
                                       float (*sopen)[256], int ntl0)
{
    const f16* __restrict__ abase = sflat + SEL*SSTR + aoff;

    f32x4 acc[7][2];
    #pragma unroll
    for (int h = 0; h < 7; ++h)
        #pragma unroll
        for (int nt = 0; nt < 2; ++nt) acc[h][nt] = (f32x4){0.f,0.f,0.f,0.f};

    f16x8 bhE[2], bhO[2];
    #pragma unroll
    for (int nt = 0; nt < 2; ++nt)
        bhE[nt] = pfrag[((ntg0+nt)*KSTEPS + 0)*128 + lane];

    #pragma clang loop unroll(disable)
    for (int it = 0; it < 5; ++it) {
        const int ks0 = 2*it, ks1 = 2*it + 1;
        const int ks2 = (ks1 == KSTEPS-1) ? (KSTEPS-1) : ks1 + 1;  // clamp, no OOB

        // ---------------- even half (ks0): uses bhE ----------------
        {
            f16x8 bl[2];
            #pragma unroll
            for (int nt = 0; nt < 2; ++nt)
                bl[nt] = pfrag[((ntg0+nt)*KSTEPS + ks0)*128 + 64 + lane];
            f16x8 ah[7];
            #pragma unroll
            for (int h = 0; h < 7; ++h)
                ah[h] = *(const f16x8*)&abase[32*ks0 - 48*h];
            __builtin_amdgcn_s_setprio(1);
            #pragma unroll
            for (int nt = 0; nt < 2; ++nt)
                #pragma unroll
                for (int h = 0; h < 7; ++h)
                    acc[h][nt] = MFMA16(ah[h], bhE[nt], acc[h][nt], 0,0,0);
            #pragma unroll
            for (int nt = 0; nt < 2; ++nt)
                #pragma unroll
                for (int h = 0; h < 7; ++h)
                    acc[h][nt] = MFMA16(ah[h], bl[nt], acc[h][nt], 0,0,0);
            __builtin_amdgcn_s_setprio(0);
            f16x8 alo[7];
            #pragma unroll
            for (int h = 0; h < 7; ++h)
                alo[h] = *(const f16x8*)&(abase + SSTR)[32*ks0 - 48*h];
            #pragma unroll
            for (int nt = 0; nt < 2; ++nt)                       // prefetch bh(ks1)
                bhO[nt] = pfrag[((ntg0+nt)*KSTEPS + ks1)*128 + lane];
            __builtin_amdgcn_s_setprio(1);
            #pragma unroll
            for (int nt = 0; nt < 2; ++nt)
                #pragma unroll
                for (int h = 0; h < 7; ++h)
                    acc[h][nt] = MFMA16(alo[h], bhE[nt], acc[h][nt], 0,0,0);
            __builtin_amdgcn_s_setprio(0);
        }

        // ---------------- odd half (ks1): uses bhO ----------------
        {
            f16x8 bl[2];
            #pragma unroll
            for (int nt = 0; nt < 2; ++nt)
                bl[nt] = pfrag[((ntg0+nt)*KSTEPS + ks1)*128 + 64 + lane];
            f16x8 ah[7];
            #pragma unroll
            for (int h = 0; h < 7; ++h)
                ah[h] = *(const f16x8*)&abase[32*ks1 - 48*h];
            __builtin_amdgcn_s_setprio(1);
            #pragma unroll
            for (int nt = 0; nt < 2; ++nt)
                #pragma unroll
                for (int h = 0; h < 7; ++h)
                    acc[h][nt] = MFMA16(ah[h], bhO[nt], acc[h][nt], 0,0,0);
            #pragma unroll
            for (int nt = 0; nt < 2; ++nt)
                #pragma unroll
                for (int h = 0; h < 7; ++h)
                    acc[h][nt] = MFMA16(ah[h], bl[nt], acc[h][nt], 0,0,0);
            __builtin_amdgcn_s_setprio(0);
            f16x8 alo[7];
            #pragma unroll
            for (int h = 0; h < 7; ++h)
                alo[h] = *(const f16x8*)&(abase + SSTR)[32*ks1 - 48*h];
            #pragma unroll
            for (int nt = 0; nt < 2; ++nt)                       // prefetch bh(ks2)
                bhE[nt] = pfrag[((ntg0+nt)*KSTEPS + ks2)*128 + lane];
            __builtin_amdgcn_s_setprio(1);
            #pragma unroll
            for (int nt = 0; nt < 2; ++nt)
                #pragma unroll
                for (int h = 0; h < 7; ++h)
                    acc[h][nt] = MFMA16(alo[h], bhO[nt], acc[h][nt], 0,0,0);
            __builtin_amdgcn_s_setprio(0);
        }
    }

    #pragma unroll
    for (int h = 0; h < 7; ++h) {
        const int ab = h*16 + rg*4;
        #pragma unroll
        for (int nt = 0; nt < 2; ++nt) {
            const float s2 = v2t + p2v[nt];
            #pragma unroll
            for (int r = 0; r < 4; ++r) {
                const int al = ab + r;
                if (al < 100) {
                    float d2 = fmaxf(fmaf(-2.f, acc[h][nt][r], s2), 0.f) * 0.01f;
                    int vlog = VOFF + al;
                    if (d2 < minD[nt]) { minD[nt] = d2; minI[nt] = vlog; }
                    if (al == 0) sopen[VOFF ? 1 : 0][(ntl0+nt)*16 + col] = d2;
                }
            }
        }
    }
}

// ---------------------------------------------------------------------------
// One block = one target t x 256 queries (blockIdx.y quarters N).  8 waves x
// 2 N-tiles; 2 sweeps (fwd, bwd).
// LDS: sext 43K + red 8K + sopen 2K = 53 KB (2 blocks/CU; register-locked at
// 4 waves/SIMD regardless -- R23 overlay measured identical).
// ---------------------------------------------------------------------------
__global__ __launch_bounds__(512) void matcher_mfma(
    const float* __restrict__ ws,      // p2 / v2 / pfrag
    const float* __restrict__ tgt,     // [256][300]
    const float* __restrict__ plog,    // [1024][2]
    const float* __restrict__ ptyp,    // [1024][4]
    const float* __restrict__ clog,    // [1024][2]
    const int*   __restrict__ labels,  // [256]
    const int*   __restrict__ iscl,    // [256]
    const float* __restrict__ clw,     // [256]
    float* __restrict__ out)           // [2][1024][256] flat fp32
{
    __shared__ __align__(16) f16 sflat[4*SSTR]; // {Fh,Fl,Rh,Rl} x 8 placed copies
    __shared__ float redD[1024];
    __shared__ int   redI[1024];
    __shared__ float sopen[2][256];

    const int t    = blockIdx.x;
    const int nb   = blockIdx.y;        // 0..3
    const int tid  = threadIdx.x;
    const int lane = tid & 63;
    const int w    = tid >> 6;
    const int col  = lane & 15;
    const int rg   = lane >> 4;
    const int ntl0 = w*2;               // local N-tile base (0..14)
    const int ntg0 = nb*16 + ntl0;      // global N-tile base

    // Stage ext (fwd+rev, hi+lo split, 8 bank-deconflicted rotated copies).
    const float* tg = tgt + t*KD;
    for (int x = tid; x < EXTLEN; x += 512) {
        int e = x - EXTOFF;
        float vF = 0.f, vR = 0.f;
        if (e >= 0 && e < 600) {
            int m = (e >= 300) ? e - 300 : e;
            vF = tg[m];
            int jj = m / 3, c3 = m - 3*jj;
            vR = tg[(NPTS-1-jj)*3 + c3];
        }
        f16 fh = (f16)vF, fl = (f16)(vF - (float)fh);
        f16 rh = (f16)vR, rl = (f16)(vR - (float)rh);
        constexpr int CB[8] = {CB_0,CB_1,CB_2,CB_3,CB_4,CB_5,CB_6,CB_7};
        #pragma unroll
        for (int c = 0; c < 8; ++c) {
            int y = x - c;
            if (y >= 0) {
                const int o = CB[c] + y;      // CB[c] compile-time (unrolled)
                sflat[0*SSTR + o] = fh; sflat[1*SSTR + o] = fl;
                sflat[2*SSTR + o] = rh; sflat[3*SSTR + o] = rl;
            }
        }
    }

    const float v2t = ws[1024 + t];
    float p2v[2];
    #pragma unroll
    for (int nt = 0; nt < 2; ++nt) p2v[nt] = ws[(ntg0+nt)*16 + col];
    const f16x8* __restrict__ pfrag = (const f16x8*)(ws + WS_PF);

    // Per-lane rotation copy and A-read base offset (hot loop adds 32ks-48h).
    const int cA = (EXTOFF + 300 - 3*col) & 7;   // lane-fixed
    const int cb = (cA==0) ? CB_0 : (cA==1) ? CB_1 : (cA==2) ? CB_2 :
                   (cA==3) ? CB_3 : (cA==4) ? CB_4 : (cA==5) ? CB_5 :
                   (cA==6) ? CB_6 : CB_7;        // cndmask chain, once
    const int aoff = cb - cA + EXTOFF + 300 - 3*col + 8*rg;
    __syncthreads();

    float minD[2]; int minI[2];
    #pragma unroll
    for (int nt = 0; nt < 2; ++nt) { minD[nt] = 3.4028235e38f; minI[nt] = 0; }

    sweep2<0,  0>(sflat, pfrag, ntg0, lane, col, rg, aoff, v2t, p2v, minD, minI, sopen, ntl0);
    sweep2<2,100>(sflat, pfrag, ntg0, lane, col, rg, aoff, v2t, p2v, minD, minI, sopen, ntl0);

    #pragma unroll
    for (int nt = 0; nt < 2; ++nt) {
        redD[(ntl0+nt)*64 + lane] = minD[nt];
        redI[(ntl0+nt)*64 + lane] = minI[nt];
    }
    __syncthreads();

    // Epilogue: threads 0..255, one local query each.
    if (tid < 256) {
        const int lq   = tid;
        const int tile = lq >> 4;
        const int cc   = lq & 15;
        const int base = tile*64 + cc;
        float bd = redD[base]; int bi = redI[base];
        #pragma unroll
        for (int g = 1; g < 4; ++g) {
            float d = redD[base + g*16]; int i = redI[base + g*16];
            if (d < bd || (d == bd && i < bi)) { bd = d; bi = i; }
        }
        const int q = nb*256 + lq;
        int mapped = (bi <= NPTS-1) ? bi : (2*NPTS-1 - bi);
        float od   = fminf(sopen[0][lq], sopen[1][lq]);
        int   isc  = iscl[t];
        float geom = isc ? bd : od;
        int   ido  = isc ? mapped : 0;
        geom *= clw[t];

        float t0 = ptyp[q*4+0], t1 = ptyp[q*4+1];
        float t2 = ptyp[q*4+2], t3 = ptyp[q*4+3];
        float mx = fmaxf(fmaxf(t0,t1), fmaxf(t2,t3));
        float e0 = expf(t0-mx), e1 = expf(t1-mx), e2 = expf(t2-mx), e3 = expf(t3-mx);
        float rs = 1.0f/(e0+e1+e2+e3);
        int lab  = labels[t];
        float el = (lab == 0) ? e0 : (lab == 1) ? e1 : (lab == 2) ? e2 : e3;
        float cost = -logf(el*rs + EPSV);
        float v0 = plog[q*2+0], v1 = plog[q*2+1];
        cost += -logf(1.0f/(1.0f + expf(v1-v0)) + EPSV);
        float c0 = clog[q*2+0], c1 = clog[q*2+1];
        float pc = isc ? (1.0f/(1.0f + expf(c0-c1))) : (1.0f/(1.0f + expf(c1-c0)));
        cost += -logf(pc + EPSV);

        float C = geom + cost;
        out[q*T_TOT + t]               = C;
        out[Q_TOT*T_TOT + q*T_TOT + t] = (float)ido;
    }
}

extern "C" void kernel_launch(void* const* d_in, const int* in_sizes, int n_in,
                              void* d_out, int out_size, void* d_ws, size_t ws_size,
                              hipStream_t stream)
{
    const float* preds  = (const float*)d_in[0];  // pred_curve_points (1,1024,100,3)
    const float* plog   = (const float*)d_in[1];  // pred_curve_logits (1,1024,2)
    const float* ptyp   = (const float*)d_in[2];  // pred_curve_type   (1,1024,4)
    const float* clog   = (const float*)d_in[3];  // closed_curve_logits (1,1024,2)
    const float* tgt    = (const float*)d_in[4];  // tgt_curve_points  (256,100,3)
    const int*   labels = (const int*)d_in[5];    // tgt_labels (256)
    const int*   iscl   = (const int*)d_in[6];    // tgt_is_closed (256)
    const float* clw    = (const float*)d_in[7];  // curve_length_weighting (256)
    float* out = (float*)d_out;
    float* ws  = (float*)d_ws;    // 1280 + 327680 floats = 1.32 MB

    prep_all    <<<dim3(64),       dim3(256), 0, stream>>>(preds, tgt, ws);
    matcher_mfma<<<dim3(T_TOT, 4), dim3(512), 0, stream>>>(
        ws, tgt, plog, ptyp, clog, labels, iscl, clw, out);
}